// Round 8
// baseline (328.250 us; speedup 1.0000x reference)
//
#include <hip/hip_runtime.h>
#include <hip/hip_bf16.h>
#include <math.h>

#define S_LEN   2048
#define HIDDEN  2048
#define NHEADS  16
#define NKVH    4
#define HDIM    128

typedef short  short8   __attribute__((ext_vector_type(8)));
typedef float  floatx4  __attribute__((ext_vector_type(4)));
typedef float  floatx16 __attribute__((ext_vector_type(16)));
typedef int    intx4    __attribute__((ext_vector_type(4)));
typedef __hip_bfloat16 bf16;

__device__ inline void async_copy16(const void* g, void* l) {
  __builtin_amdgcn_global_load_lds((__attribute__((address_space(1))) void*)(g),
                                   (__attribute__((address_space(3))) void*)(l),
                                   16, 0, 0);
}

__device__ inline unsigned short cvt1(float x) {
  bf16 t = __float2bfloat16(x);
  return *reinterpret_cast<unsigned short*>(&t);
}
__device__ inline float us2f(unsigned short u) {
  unsigned int v = ((unsigned int)u) << 16;
  return *reinterpret_cast<float*>(&v);
}

// fp32 -> bf16 for all three inputs in one launch; dst regions contiguous.
#define N8_H  1048576
#define N8_WQ  786432
#define N8_WO  524288
__global__ __launch_bounds__(256) void cvt_all(const float* __restrict__ h,
                                               const float* __restrict__ wq,
                                               const float* __restrict__ wo,
                                               unsigned short* __restrict__ dst) {
  const int i = blockIdx.x * 256 + threadIdx.x;
  if (i >= N8_H + N8_WQ + N8_WO) return;
  const float* src; int j;
  if (i < N8_H)              { src = h;  j = i; }
  else if (i < N8_H + N8_WQ) { src = wq; j = i - N8_H; }
  else                       { src = wo; j = i - N8_H - N8_WQ; }
  const float4 a = reinterpret_cast<const float4*>(src)[j * 2];
  const float4 b = reinterpret_cast<const float4*>(src)[j * 2 + 1];
  unsigned short o[8] = {cvt1(a.x), cvt1(a.y), cvt1(a.z), cvt1(a.w),
                         cvt1(b.x), cvt1(b.y), cvt1(b.z), cvt1(b.w)};
  *reinterpret_cast<short8*>(dst + (size_t)i * 8) = *reinterpret_cast<short8*>(o);
}

// ============================================================================
// 8-wave pipelined GEMM (unchanged from round 7).
// ============================================================================
template<int MODE>
__global__ __launch_bounds__(512, 2) void gemm8(const bf16* __restrict__ A,
                                                const bf16* __restrict__ B,
                                                bf16* __restrict__ qbuf,
                                                bf16* __restrict__ kbuf,
                                                bf16* __restrict__ vtbuf,
                                                float* __restrict__ Cout)
{
  constexpr int K      = 2048;
  constexpr int BM     = (MODE == 0) ? 256 : 128;
  constexpr int BN     = 256;
  constexpr int MF     = BM / 32;
  constexpr int AI     = BM / 128;
  constexpr int ABYTES = BM * 64;
  constexpr int SLOT   = (BM + BN) * 64;
  constexpr int NSTEP  = K / 32;

  __shared__ __align__(16) unsigned short smem[SLOT * 4 / 2];
  char* smb = (char*)smem;

  const int bn = blockIdx.x, bm = blockIdx.y;
  const int t = threadIdx.x, w = t >> 6, lane = t & 63;
  const int m16 = lane & 15, quad = lane >> 4;
  const int wmr = (w >> 2) * (BM / 2);
  const int wn  = w & 3;

  int bcol[4];
#pragma unroll
  for (int ni = 0; ni < 4; ++ni)
    bcol[ni] = (MODE == 0)
             ? ((wn >> 1) * 128 + (wn & 1) * 32 + (ni & 1) * 16 + (ni >> 1) * 64)
             : (wn * 64 + ni * 16);

  int afo[MF], bfo[4];
#pragma unroll
  for (int mf = 0; mf < MF; ++mf) {
    const int r = wmr + mf * 16 + m16;
    afo[mf] = r * 64 + ((quad ^ ((r >> 1) & 3)) << 4);
  }
#pragma unroll
  for (int ni = 0; ni < 4; ++ni) {
    const int r = bcol[ni] + m16;
    bfo[ni] = ABYTES + r * 64 + ((quad ^ ((r >> 1) & 3)) << 4);
  }

  const bf16* srcA[AI]; int dstA[AI];
#pragma unroll
  for (int j = 0; j < AI; ++j) {
    const int ci  = w * AI + j;
    const int row = ci * 16 + (lane >> 2);
    const int sl  = (lane & 3) ^ ((row >> 1) & 3);
    srcA[j] = A + (size_t)(bm * BM + row) * K + sl * 8;
    dstA[j] = ci * 1024;
  }
  const bf16* srcB[2]; int dstB[2];
#pragma unroll
  for (int j = 0; j < 2; ++j) {
    const int ci  = w * 2 + j;
    const int row = ci * 16 + (lane >> 2);
    const int sl  = (lane & 3) ^ ((row >> 1) & 3);
    srcB[j] = B + (size_t)(bn * BN + row) * K + sl * 8;
    dstB[j] = ABYTES + ci * 1024;
  }

  auto stage = [&](int step, int slotbyte) {
#pragma unroll
    for (int j = 0; j < AI; ++j)
      async_copy16(srcA[j] + step * 32, smb + slotbyte + dstA[j]);
#pragma unroll
    for (int j = 0; j < 2; ++j)
      async_copy16(srcB[j] + step * 32, smb + slotbyte + dstB[j]);
  };

  const floatx4 zf = {0.f, 0.f, 0.f, 0.f};
  floatx4 acc[MF][4];
#pragma unroll
  for (int mf = 0; mf < MF; ++mf)
#pragma unroll
    for (int ni = 0; ni < 4; ++ni) acc[mf][ni] = zf;

  stage(0, 0); stage(1, SLOT); stage(2, 2 * SLOT);

#pragma unroll 4
  for (int s = 0; s < NSTEP; ++s) {
    __builtin_amdgcn_sched_barrier(0);
    if constexpr (MODE == 0) asm volatile("s_waitcnt vmcnt(8)" ::: "memory");
    else                     asm volatile("s_waitcnt vmcnt(6)" ::: "memory");
    __builtin_amdgcn_s_barrier();
    __builtin_amdgcn_sched_barrier(0);
    const int sb  = (s & 3) * SLOT;
    const int ns  = (s + 3) & (NSTEP - 1);
    const int nsb = ((s + 3) & 3) * SLOT;
    if constexpr (MODE == 0) {
      short8 bfr[4], afA[4];
#pragma unroll
      for (int ni = 0; ni < 4; ++ni)
        bfr[ni] = *reinterpret_cast<const short8*>(smb + sb + bfo[ni]);
#pragma unroll
      for (int mf = 0; mf < 4; ++mf)
        afA[mf] = *reinterpret_cast<const short8*>(smb + sb + afo[mf]);
#pragma unroll
      for (int j = 0; j < AI; ++j)
        async_copy16(srcA[j] + ns * 32, smb + nsb + dstA[j]);
      asm volatile("s_waitcnt lgkmcnt(0)" ::: "memory");
      __builtin_amdgcn_sched_barrier(0);
      __builtin_amdgcn_s_setprio(1);
#pragma unroll
      for (int mf = 0; mf < 4; ++mf)
#pragma unroll
        for (int ni = 0; ni < 4; ++ni)
          acc[mf][ni] = __builtin_amdgcn_mfma_f32_16x16x32_bf16(afA[mf], bfr[ni], acc[mf][ni], 0, 0, 0);
      __builtin_amdgcn_s_setprio(0);
      __builtin_amdgcn_s_barrier();
      short8 afB[4];
#pragma unroll
      for (int mf = 0; mf < 4; ++mf)
        afB[mf] = *reinterpret_cast<const short8*>(smb + sb + afo[4 + mf]);
#pragma unroll
      for (int j = 0; j < 2; ++j)
        async_copy16(srcB[j] + ns * 32, smb + nsb + dstB[j]);
      asm volatile("s_waitcnt lgkmcnt(0)" ::: "memory");
      __builtin_amdgcn_sched_barrier(0);
      __builtin_amdgcn_s_setprio(1);
#pragma unroll
      for (int mf = 0; mf < 4; ++mf)
#pragma unroll
        for (int ni = 0; ni < 4; ++ni)
          acc[4 + mf][ni] = __builtin_amdgcn_mfma_f32_16x16x32_bf16(afB[mf], bfr[ni], acc[4 + mf][ni], 0, 0, 0);
      __builtin_amdgcn_s_setprio(0);
    } else {
      short8 af[MF], bfr[4];
#pragma unroll
      for (int mf = 0; mf < MF; ++mf)
        af[mf] = *reinterpret_cast<const short8*>(smb + sb + afo[mf]);
#pragma unroll
      for (int ni = 0; ni < 4; ++ni)
        bfr[ni] = *reinterpret_cast<const short8*>(smb + sb + bfo[ni]);
      stage(ns, nsb);
      __builtin_amdgcn_s_setprio(1);
#pragma unroll
      for (int mf = 0; mf < MF; ++mf)
#pragma unroll
        for (int ni = 0; ni < 4; ++ni)
          acc[mf][ni] = __builtin_amdgcn_mfma_f32_16x16x32_bf16(af[mf], bfr[ni], acc[mf][ni], 0, 0, 0);
      __builtin_amdgcn_s_setprio(0);
    }
  }
  __builtin_amdgcn_s_waitcnt(0);

  if constexpr (MODE == 1) {
#pragma unroll
    for (int mf = 0; mf < MF; ++mf)
#pragma unroll
      for (int ni = 0; ni < 4; ++ni) {
        const int row0 = bm * BM + wmr + mf * 16 + quad * 4;
        const int col  = bn * BN + bcol[ni] + m16;
#pragma unroll
        for (int r = 0; r < 4; ++r)
          Cout[(size_t)(row0 + r) * HIDDEN + col] = acc[mf][ni][r];
      }
  } else {
    const int colbase = bn * BN;
    if (colbase < HIDDEN + NKVH * HDIM) {
      const bool isQ = (colbase < HIDDEN);
      const float post = isQ ? 0.08838834764831845f : 1.0f;
      float invf[2];
#pragma unroll
      for (int p = 0; p < 2; ++p)
        invf[p] = exp2f((float)((wn & 1) * 32 + p * 16 + m16) * -0.2076205059f);
#pragma unroll
      for (int mf = 0; mf < MF; ++mf) {
        const int row0 = bm * BM + wmr + mf * 16 + quad * 4;
#pragma unroll
        for (int r = 0; r < 4; ++r) {
          const int m = row0 + r;
          const int b = m >> 11, s = m & 2047;
          float sn[2], cs[2];
          __sincosf((float)s * invf[0], &sn[0], &cs[0]);
          __sincosf((float)s * invf[1], &sn[1], &cs[1]);
#pragma unroll
          for (int ni = 0; ni < 4; ++ni) {
            const int p = ni & 1;
            const float v  = acc[mf][ni][r];
            const float v2 = acc[mf][ni ^ 2][r];
            const float rot = ((ni < 2) ? (v * cs[p] - v2 * sn[p])
                                        : (v * cs[p] + v2 * sn[p])) * post;
            const int col = colbase + bcol[ni] + m16;
            if (isQ) {
              const int hh = col >> 7, d = col & 127;
              qbuf[(((size_t)(b * NHEADS + hh)) * S_LEN + s) * HDIM + d] = __float2bfloat16(rot);
            } else {
              const int nn = col - HIDDEN; const int hh = nn >> 7, d = nn & 127;
              kbuf[(((size_t)(b * NKVH + hh)) * S_LEN + s) * HDIM + d] = __float2bfloat16(rot);
            }
          }
        }
      }
    } else {
#pragma unroll
      for (int mf = 0; mf < MF; ++mf)
#pragma unroll
        for (int ni = 0; ni < 4; ++ni) {
          const int col = colbase + bcol[ni] + m16;
          const int nn = col - HIDDEN - NKVH * HDIM;
          const int hh = nn >> 7, d = nn & 127;
          const int row0 = bm * BM + wmr + mf * 16 + quad * 4;
#pragma unroll
          for (int r = 0; r < 4; ++r) {
            const int m = row0 + r;
            const int b = m >> 11, s = m & 2047;
            vtbuf[(((size_t)(b * NKVH + hh)) * HDIM + d) * S_LEN + s] =
                __float2bfloat16(acc[mf][ni][r]);
          }
        }
    }
  }
}

// ---------------- Attention phase A: swapped-QK 32x32, in-register P ---------
// T12: compute mfma(K, Q) with 32x32x16 so D[key][qrow] has col=lane&31=qrow,
// row=crow(r,hi)=(r&3)+8*(r>>2)+4*hi=key. Each lane then holds 16 P-values of
// ITS OWN q-row; the PV A-fragment (lane needs P[lane&31][hi*8+j]) is built
// in registers: 8 bf16-packs + 8 shfl_xor(32) + selects. No P LDS buffer,
// no ds_write->lgkm->ds_read chain. Row-sums via MFMA-with-ones land lacc[r]
// aligned with oacc rows. Frag build table (verified on paper):
//   frag0(keys 0-15):  hi=0 -> [c0,c1,P(c0),P(c1)]  hi=1 -> [P(c2),P(c3),c2,c3]
//   frag1(keys 16-31): hi=0 -> [c4,c5,P(c4),P(c5)]  hi=1 -> [P(c6),P(c7),c6,c7]
// where c[t]=pack(p[2t],p[2t+1]), P = shfl_xor(.,32).
// Split-K chunking, ring-4 K/V staging, and the two-tile score pipeline are
// unchanged from round 6. K LDS swizzle upgraded to 4-bit XOR (2-way, free).
__global__ __launch_bounds__(256) void attn_partial(const bf16* __restrict__ qbuf,
                                                    const bf16* __restrict__ kbuf,
                                                    const bf16* __restrict__ vtbuf,
                                                    unsigned short* __restrict__ pnum,
                                                    float* __restrict__ plsum,
                                                    bf16* __restrict__ abuf)
{
  __shared__ unsigned short Ks[4][4096];
  __shared__ unsigned short Vs[4][4096];
  const int sidx = 110 - blockIdx.x;       // descending dispatch
  int i2, c, nch;
  if (sidx < 27)      { i2 = sidx;                     c = 0;              nch = 1; }
  else if (sidx < 81) { i2 = 27 + ((sidx - 27) >> 1);  c = (sidx - 27) & 1; nch = 2; }
  else                { i2 = 54 + (sidx - 81) / 3;     c = (sidx - 81) % 3; nch = 3; }
  const int len = i2 + 1;
  const int k0 = (c * len) / nch, k1 = ((c + 1) * len) / nch;
  const int kvh = blockIdx.y, b = blockIdx.z;
  const int t = threadIdx.x, w = t >> 6, lane = t & 63;
  const int l31 = lane & 31, hi = lane >> 5;
  const int h = kvh * 4 + w;

  // Q as B-operand: lane holds Q[qrow=l31][d = cc*16 + hi*8 + j]
  const bf16* Qp = qbuf + (((size_t)(b * NHEADS + h)) * S_LEN + i2 * 32 + l31) * HDIM;
  short8 qf[8];
#pragma unroll
  for (int cc = 0; cc < 8; ++cc)
    qf[cc] = *reinterpret_cast<const short8*>(Qp + cc * 16 + hi * 8);

  const bf16* Kp  = kbuf  + ((size_t)(b * NKVH + kvh)) * S_LEN * HDIM;
  const bf16* Vtp = vtbuf + ((size_t)(b * NKVH + kvh)) * HDIM * S_LEN;

  // staging offsets: K tile [32 keys][128 d] with 4-bit chunk XOR;
  // V tile [128 d][32 keys] with 2-bit chunk XOR (as before).
  const int kk = lane >> 4, cK = lane & 15;
  const int rKa = w * 8 + kk, rKb = rKa + 4;
  const int offKa = rKa * 128 + ((cK ^ (rKa & 15)) * 8);
  const int offKb = rKb * 128 + ((cK ^ (rKb & 15)) * 8);
  const int dd = lane >> 2, cV = lane & 3;
  const int dVa = w * 32 + dd, dVb = dVa + 16;
  const int offVa = dVa * 2048 + ((cV ^ ((dVa >> 1) & 3)) * 8);
  const int offVb = dVb * 2048 + ((cV ^ ((dVb >> 1) & 3)) * 8);

  floatx16 oacc[4], lacc;
#pragma unroll
  for (int i = 0; i < 16; ++i) { lacc[i] = 0.f; oacc[0][i] = 0.f; oacc[1][i] = 0.f; oacc[2][i] = 0.f; oacc[3][i] = 0.f; }
  unsigned short ones_s[8] = {0x3F80,0x3F80,0x3F80,0x3F80,0x3F80,0x3F80,0x3F80,0x3F80};
  const short8 ones = *reinterpret_cast<short8*>(ones_s);

  auto stage_tile = [&](int kt) {
    const int sl = kt & 3;
    const int ks = kt * 32;
    async_copy16(Kp + (size_t)ks * 128 + offKa, &Ks[sl][w * 1024]);
    async_copy16(Kp + (size_t)ks * 128 + offKb, &Ks[sl][w * 1024 + 512]);
    async_copy16(Vtp + ks + offVa, &Vs[sl][w * 1024]);
    async_copy16(Vtp + ks + offVb, &Vs[sl][w * 1024 + 512]);
  };

  auto qk = [&](int kt, floatx16& s) {
    const int sl = kt & 3;
#pragma unroll
    for (int i = 0; i < 16; ++i) s[i] = 0.f;
#pragma unroll
    for (int cc = 0; cc < 8; ++cc) {
      const short8 kf = *reinterpret_cast<const short8*>(
          &Ks[sl][l31 * 128 + (((cc * 2 + hi) ^ (l31 & 15)) * 8)]);
      s = __builtin_amdgcn_mfma_f32_32x32x16_bf16(kf, qf[cc], s, 0, 0, 0);
    }
  };

  auto finish = [&](int kt, const floatx16& s) {
    const int sl = kt & 3;
    const int ks = kt * 32;
    const int qrow = i2 * 32 + l31;
    unsigned int cw[8];
#pragma unroll
    for (int tt = 0; tt < 8; ++tt) {
      const int r0 = 2 * tt;
      const int key0 = ks + (r0 & 3) + 8 * (r0 >> 2) + 4 * hi;
      const float p0 = (key0     > qrow) ? 0.f : __expf(s[r0]);
      const float p1 = (key0 + 1 > qrow) ? 0.f : __expf(s[r0 + 1]);
      cw[tt] = ((unsigned int)cvt1(p1) << 16) | cvt1(p0);
    }
    unsigned int pc[8];
#pragma unroll
    for (int tt = 0; tt < 8; ++tt) pc[tt] = (unsigned int)__shfl_xor((int)cw[tt], 32);
    intx4 f0, f1;
    f0[0] = (int)(hi ? pc[2] : cw[0]); f0[1] = (int)(hi ? pc[3] : cw[1]);
    f0[2] = (int)(hi ? cw[2] : pc[0]); f0[3] = (int)(hi ? cw[3] : pc[1]);
    f1[0] = (int)(hi ? pc[6] : cw[4]); f1[1] = (int)(hi ? pc[7] : cw[5]);
    f1[2] = (int)(hi ? cw[6] : pc[4]); f1[3] = (int)(hi ? cw[7] : pc[5]);
    const short8 pf0 = __builtin_bit_cast(short8, f0);
    const short8 pf1 = __builtin_bit_cast(short8, f1);
    lacc = __builtin_amdgcn_mfma_f32_32x32x16_bf16(pf0, ones, lacc, 0, 0, 0);
    lacc = __builtin_amdgcn_mfma_f32_32x32x16_bf16(pf1, ones, lacc, 0, 0, 0);
#pragma unroll
    for (int db = 0; db < 4; ++db) {
      const int drow = db * 32 + l31;
      const int xr = (drow >> 1) & 3;
      const short8 vf0 = *reinterpret_cast<const short8*>(
          &Vs[sl][drow * 32 + ((hi ^ xr) * 8)]);
      oacc[db] = __builtin_amdgcn_mfma_f32_32x32x16_bf16(pf0, vf0, oacc[db], 0, 0, 0);
      const short8 vf1 = *reinterpret_cast<const short8*>(
          &Vs[sl][drow * 32 + (((2 + hi) ^ xr) * 8)]);
      oacc[db] = __builtin_amdgcn_mfma_f32_32x32x16_bf16(pf1, vf1, oacc[db], 0, 0, 0);
    }
  };

  // Prologue: stage tiles k0, k0+1; barrier drains them (incl. Q loads); QK k0.
  stage_tile(k0);
  if (k0 + 1 < k1) stage_tile(k0 + 1);
  __syncthreads();
  floatx16 sa, sb;
  qk(k0, sa);

  int ki = k0 + 1;
  for (; ki + 1 < k1; ki += 2) {
    stage_tile(ki + 1);
    qk(ki, sb);
    finish(ki - 1, sa);
    __syncthreads();
    if (ki + 2 < k1) stage_tile(ki + 2);
    qk(ki + 1, sa);
    finish(ki, sb);
    __syncthreads();
  }
  if (ki < k1) {
    qk(ki, sb);
    finish(ki - 1, sa);
    finish(ki, sb);
  } else {
    finish(ki - 1, sa);
  }

  if (nch == 1) {
    float invl[16];
#pragma unroll
    for (int r = 0; r < 16; ++r) invl[r] = 1.0f / lacc[r];
#pragma unroll
    for (int db = 0; db < 4; ++db)
#pragma unroll
      for (int r = 0; r < 16; ++r) {
        const int row = i2 * 32 + (r & 3) + 8 * (r >> 2) + 4 * hi;
        abuf[(((size_t)b * S_LEN + row) * NHEADS + h) * HDIM + db * 32 + l31] =
            __float2bfloat16(oacc[db][r] * invl[r]);
      }
  } else {
    const int b0 = (i2 < 54) ? (27 + 2 * (i2 - 27)) : (81 + 3 * (i2 - 54));
    const int slot = (b * NHEADS + h) * 111 + b0 + c;
    unsigned short* np = pnum + (size_t)slot * 4096;
#pragma unroll
    for (int db = 0; db < 4; ++db)
#pragma unroll
      for (int r = 0; r < 16; ++r) {
        const int row = (r & 3) + 8 * (r >> 2) + 4 * hi;
        np[row * 128 + db * 32 + l31] = cvt1(oacc[db][r]);
      }
    if (l31 == 0) {
#pragma unroll
      for (int r = 0; r < 16; ++r)
        plsum[slot * 32 + (r & 3) + 8 * (r >> 2) + 4 * hi] = lacc[r];
    }
  }
}

// ---------------- Attention phase B: combine multi-chunk tiles only ----------
__global__ __launch_bounds__(256) void attn_combine(const unsigned short* __restrict__ pnum,
                                                    const float* __restrict__ plsum,
                                                    bf16* __restrict__ abuf)
{
  const int i = 54 + blockIdx.x;                     // 16-row tiles 54..127
  const int h = blockIdx.y, b = blockIdx.z;
  const int i2 = i >> 1, lr0 = (i & 1) * 16;
  const int t = threadIdx.x, row16 = t >> 4, c0 = (t & 15) * 8;
  const int lr = lr0 + row16;
  const int nch = (i2 < 54) ? 2 : 3;
  const int b0  = (i2 < 54) ? (27 + 2 * (i2 - 27)) : (81 + 3 * (i2 - 54));
  const int hb = (b * NHEADS + h) * 111 + b0;
  float acc[8] = {0.f,0.f,0.f,0.f,0.f,0.f,0.f,0.f};
  float lsum = 0.f;
  for (int c = 0; c < nch; ++c) {
    const unsigned short* np = pnum + (size_t)(hb + c) * 4096 + lr * 128 + c0;
    const short8 v = *reinterpret_cast<const short8*>(np);
#pragma unroll
    for (int j = 0; j < 8; ++j) acc[j] += us2f(((unsigned short*)&v)[j]);
    lsum += plsum[(hb + c) * 32 + lr];
  }
  const float invl = 1.0f / lsum;
  unsigned short o[8];
#pragma unroll
  for (int j = 0; j < 8; ++j) o[j] = cvt1(acc[j] * invl);
  *reinterpret_cast<short8*>(abuf + (((size_t)b * S_LEN + i * 16 + row16) * NHEADS + h) * HDIM + c0)
      = *reinterpret_cast<short8*>(o);
}

extern "C" void kernel_launch(void* const* d_in, const int* in_sizes, int n_in,
                              void* d_out, int out_size, void* d_ws, size_t ws_size,
                              hipStream_t stream) {
  const float* hidden_f = (const float*)d_in[0];
  const float* wqkv_f   = (const float*)d_in[1];
  const float* wout_f   = (const float*)d_in[2];
  float* out = (float*)d_out;

  char* ws = (char*)d_ws;
  bf16* hbf    = (bf16*)(ws);                    // [4096,2048]   (dead after gemm0)
  bf16* wqkvbf = (bf16*)(ws + 16777216);         // [3072,2048]   (dead after gemm0)
  bf16* woutbf = (bf16*)(ws + 29360128);         // [2048,2048]
  bf16* qbuf   = (bf16*)(ws + 37748736);         // [B,NH,S,HD]
  bf16* kbuf   = (bf16*)(ws + 54525952);         // [B,NKV,S,HD]
  bf16* vtbuf  = (bf16*)(ws + 58720256);         // [B,NKV,HD,S]
  bf16* abuf   = (bf16*)(ws + 62914560);         // [B,S,NH,HD]
  unsigned short* pnum = (unsigned short*)(ws);  // overlay: 3552 x 8KB = 29.1 MB
  float* plsum = (float*)(ws + 79691776);        // 3552 x 32 fp32 (0.45 MB)

  cvt_all<<<9216, 256, 0, stream>>>(hidden_f, wqkv_f, wout_f, (unsigned short*)ws);

  gemm8<0><<<dim3(12, 16), 512, 0, stream>>>(hbf, wqkvbf, qbuf, kbuf, vtbuf, nullptr);
  attn_partial<<<dim3(111, 4, 2), 256, 0, stream>>>(qbuf, kbuf, vtbuf, pnum, plsum, abuf);
  attn_combine<<<dim3(74, 16, 2), 256, 0, stream>>>(pnum, plsum, abuf);
  gemm8<1><<<dim3(8, 32), 512, 0, stream>>>(abuf, woutbf, nullptr, nullptr, nullptr, out);
}

// Round 9
// 328.115 us; speedup vs baseline: 1.0004x; 1.0004x over previous
//
#include <hip/hip_runtime.h>
#include <hip/hip_bf16.h>
#include <math.h>

#define S_LEN   2048
#define HIDDEN  2048
#define NHEADS  16
#define NKVH    4
#define HDIM    128

typedef short  short8  __attribute__((ext_vector_type(8)));
typedef float  floatx4 __attribute__((ext_vector_type(4)));
typedef __hip_bfloat16 bf16;

__device__ inline void async_copy16(const void* g, void* l) {
  __builtin_amdgcn_global_load_lds((__attribute__((address_space(1))) void*)(g),
                                   (__attribute__((address_space(3))) void*)(l),
                                   16, 0, 0);
}

__device__ inline unsigned short cvt1(float x) {
  bf16 t = __float2bfloat16(x);
  return *reinterpret_cast<unsigned short*>(&t);
}
__device__ inline float us2f(unsigned short u) {
  unsigned int v = ((unsigned int)u) << 16;
  return *reinterpret_cast<float*>(&v);
}

// fp32 -> bf16 for all three inputs in one launch; dst regions contiguous.
#define N8_H  1048576
#define N8_WQ  786432
#define N8_WO  524288
__global__ __launch_bounds__(256) void cvt_all(const float* __restrict__ h,
                                               const float* __restrict__ wq,
                                               const float* __restrict__ wo,
                                               unsigned short* __restrict__ dst) {
  const int i = blockIdx.x * 256 + threadIdx.x;
  if (i >= N8_H + N8_WQ + N8_WO) return;
  const float* src; int j;
  if (i < N8_H)              { src = h;  j = i; }
  else if (i < N8_H + N8_WQ) { src = wq; j = i - N8_H; }
  else                       { src = wo; j = i - N8_H - N8_WQ; }
  const float4 a = reinterpret_cast<const float4*>(src)[j * 2];
  const float4 b = reinterpret_cast<const float4*>(src)[j * 2 + 1];
  unsigned short o[8] = {cvt1(a.x), cvt1(a.y), cvt1(a.z), cvt1(a.w),
                         cvt1(b.x), cvt1(b.y), cvt1(b.z), cvt1(b.w)};
  *reinterpret_cast<short8*>(dst + (size_t)i * 8) = *reinterpret_cast<short8*>(o);
}

// ============================================================================
// 8-wave pipelined GEMM (unchanged from round 7).
// ============================================================================
template<int MODE>
__global__ __launch_bounds__(512, 2) void gemm8(const bf16* __restrict__ A,
                                                const bf16* __restrict__ B,
                                                bf16* __restrict__ qbuf,
                                                bf16* __restrict__ kbuf,
                                                bf16* __restrict__ vtbuf,
                                                float* __restrict__ Cout)
{
  constexpr int K      = 2048;
  constexpr int BM     = (MODE == 0) ? 256 : 128;
  constexpr int BN     = 256;
  constexpr int MF     = BM / 32;
  constexpr int AI     = BM / 128;
  constexpr int ABYTES = BM * 64;
  constexpr int SLOT   = (BM + BN) * 64;
  constexpr int NSTEP  = K / 32;

  __shared__ __align__(16) unsigned short smem[SLOT * 4 / 2];
  char* smb = (char*)smem;

  const int bn = blockIdx.x, bm = blockIdx.y;
  const int t = threadIdx.x, w = t >> 6, lane = t & 63;
  const int m16 = lane & 15, quad = lane >> 4;
  const int wmr = (w >> 2) * (BM / 2);
  const int wn  = w & 3;

  int bcol[4];
#pragma unroll
  for (int ni = 0; ni < 4; ++ni)
    bcol[ni] = (MODE == 0)
             ? ((wn >> 1) * 128 + (wn & 1) * 32 + (ni & 1) * 16 + (ni >> 1) * 64)
             : (wn * 64 + ni * 16);

  int afo[MF], bfo[4];
#pragma unroll
  for (int mf = 0; mf < MF; ++mf) {
    const int r = wmr + mf * 16 + m16;
    afo[mf] = r * 64 + ((quad ^ ((r >> 1) & 3)) << 4);
  }
#pragma unroll
  for (int ni = 0; ni < 4; ++ni) {
    const int r = bcol[ni] + m16;
    bfo[ni] = ABYTES + r * 64 + ((quad ^ ((r >> 1) & 3)) << 4);
  }

  const bf16* srcA[AI]; int dstA[AI];
#pragma unroll
  for (int j = 0; j < AI; ++j) {
    const int ci  = w * AI + j;
    const int row = ci * 16 + (lane >> 2);
    const int sl  = (lane & 3) ^ ((row >> 1) & 3);
    srcA[j] = A + (size_t)(bm * BM + row) * K + sl * 8;
    dstA[j] = ci * 1024;
  }
  const bf16* srcB[2]; int dstB[2];
#pragma unroll
  for (int j = 0; j < 2; ++j) {
    const int ci  = w * 2 + j;
    const int row = ci * 16 + (lane >> 2);
    const int sl  = (lane & 3) ^ ((row >> 1) & 3);
    srcB[j] = B + (size_t)(bn * BN + row) * K + sl * 8;
    dstB[j] = ABYTES + ci * 1024;
  }

  auto stage = [&](int step, int slotbyte) {
#pragma unroll
    for (int j = 0; j < AI; ++j)
      async_copy16(srcA[j] + step * 32, smb + slotbyte + dstA[j]);
#pragma unroll
    for (int j = 0; j < 2; ++j)
      async_copy16(srcB[j] + step * 32, smb + slotbyte + dstB[j]);
  };

  const floatx4 zf = {0.f, 0.f, 0.f, 0.f};
  floatx4 acc[MF][4];
#pragma unroll
  for (int mf = 0; mf < MF; ++mf)
#pragma unroll
    for (int ni = 0; ni < 4; ++ni) acc[mf][ni] = zf;

  stage(0, 0); stage(1, SLOT); stage(2, 2 * SLOT);

#pragma unroll 4
  for (int s = 0; s < NSTEP; ++s) {
    __builtin_amdgcn_sched_barrier(0);
    if constexpr (MODE == 0) asm volatile("s_waitcnt vmcnt(8)" ::: "memory");
    else                     asm volatile("s_waitcnt vmcnt(6)" ::: "memory");
    __builtin_amdgcn_s_barrier();
    __builtin_amdgcn_sched_barrier(0);
    const int sb  = (s & 3) * SLOT;
    const int ns  = (s + 3) & (NSTEP - 1);
    const int nsb = ((s + 3) & 3) * SLOT;
    if constexpr (MODE == 0) {
      short8 bfr[4], afA[4];
#pragma unroll
      for (int ni = 0; ni < 4; ++ni)
        bfr[ni] = *reinterpret_cast<const short8*>(smb + sb + bfo[ni]);
#pragma unroll
      for (int mf = 0; mf < 4; ++mf)
        afA[mf] = *reinterpret_cast<const short8*>(smb + sb + afo[mf]);
#pragma unroll
      for (int j = 0; j < AI; ++j)
        async_copy16(srcA[j] + ns * 32, smb + nsb + dstA[j]);
      asm volatile("s_waitcnt lgkmcnt(0)" ::: "memory");
      __builtin_amdgcn_sched_barrier(0);
      __builtin_amdgcn_s_setprio(1);
#pragma unroll
      for (int mf = 0; mf < 4; ++mf)
#pragma unroll
        for (int ni = 0; ni < 4; ++ni)
          acc[mf][ni] = __builtin_amdgcn_mfma_f32_16x16x32_bf16(afA[mf], bfr[ni], acc[mf][ni], 0, 0, 0);
      __builtin_amdgcn_s_setprio(0);
      __builtin_amdgcn_s_barrier();
      short8 afB[4];
#pragma unroll
      for (int mf = 0; mf < 4; ++mf)
        afB[mf] = *reinterpret_cast<const short8*>(smb + sb + afo[4 + mf]);
#pragma unroll
      for (int j = 0; j < 2; ++j)
        async_copy16(srcB[j] + ns * 32, smb + nsb + dstB[j]);
      asm volatile("s_waitcnt lgkmcnt(0)" ::: "memory");
      __builtin_amdgcn_sched_barrier(0);
      __builtin_amdgcn_s_setprio(1);
#pragma unroll
      for (int mf = 0; mf < 4; ++mf)
#pragma unroll
        for (int ni = 0; ni < 4; ++ni)
          acc[4 + mf][ni] = __builtin_amdgcn_mfma_f32_16x16x32_bf16(afB[mf], bfr[ni], acc[4 + mf][ni], 0, 0, 0);
      __builtin_amdgcn_s_setprio(0);
    } else {
      short8 af[MF], bfr[4];
#pragma unroll
      for (int mf = 0; mf < MF; ++mf)
        af[mf] = *reinterpret_cast<const short8*>(smb + sb + afo[mf]);
#pragma unroll
      for (int ni = 0; ni < 4; ++ni)
        bfr[ni] = *reinterpret_cast<const short8*>(smb + sb + bfo[ni]);
      stage(ns, nsb);
      __builtin_amdgcn_s_setprio(1);
#pragma unroll
      for (int mf = 0; mf < MF; ++mf)
#pragma unroll
        for (int ni = 0; ni < 4; ++ni)
          acc[mf][ni] = __builtin_amdgcn_mfma_f32_16x16x32_bf16(af[mf], bfr[ni], acc[mf][ni], 0, 0, 0);
      __builtin_amdgcn_s_setprio(0);
    }
  }
  __builtin_amdgcn_s_waitcnt(0);

  if constexpr (MODE == 1) {
#pragma unroll
    for (int mf = 0; mf < MF; ++mf)
#pragma unroll
      for (int ni = 0; ni < 4; ++ni) {
        const int row0 = bm * BM + wmr + mf * 16 + quad * 4;
        const int col  = bn * BN + bcol[ni] + m16;
#pragma unroll
        for (int r = 0; r < 4; ++r)
          Cout[(size_t)(row0 + r) * HIDDEN + col] = acc[mf][ni][r];
      }
  } else {
    const int colbase = bn * BN;
    if (colbase < HIDDEN + NKVH * HDIM) {
      const bool isQ = (colbase < HIDDEN);
      const float post = isQ ? 0.08838834764831845f : 1.0f;
      float invf[2];
#pragma unroll
      for (int p = 0; p < 2; ++p)
        invf[p] = exp2f((float)((wn & 1) * 32 + p * 16 + m16) * -0.2076205059f);
#pragma unroll
      for (int mf = 0; mf < MF; ++mf) {
        const int row0 = bm * BM + wmr + mf * 16 + quad * 4;
#pragma unroll
        for (int r = 0; r < 4; ++r) {
          const int m = row0 + r;
          const int b = m >> 11, s = m & 2047;
          float sn[2], cs[2];
          __sincosf((float)s * invf[0], &sn[0], &cs[0]);
          __sincosf((float)s * invf[1], &sn[1], &cs[1]);
#pragma unroll
          for (int ni = 0; ni < 4; ++ni) {
            const int p = ni & 1;
            const float v  = acc[mf][ni][r];
            const float v2 = acc[mf][ni ^ 2][r];
            const float rot = ((ni < 2) ? (v * cs[p] - v2 * sn[p])
                                        : (v * cs[p] + v2 * sn[p])) * post;
            const int col = colbase + bcol[ni] + m16;
            if (isQ) {
              const int hh = col >> 7, d = col & 127;
              qbuf[(((size_t)(b * NHEADS + hh)) * S_LEN + s) * HDIM + d] = __float2bfloat16(rot);
            } else {
              const int nn = col - HIDDEN; const int hh = nn >> 7, d = nn & 127;
              kbuf[(((size_t)(b * NKVH + hh)) * S_LEN + s) * HDIM + d] = __float2bfloat16(rot);
            }
          }
        }
      }
    } else {
#pragma unroll
      for (int mf = 0; mf < MF; ++mf)
#pragma unroll
        for (int ni = 0; ni < 4; ++ni) {
          const int col = colbase + bcol[ni] + m16;
          const int nn = col - HIDDEN - NKVH * HDIM;
          const int hh = nn >> 7, d = nn & 127;
          const int row0 = bm * BM + wmr + mf * 16 + quad * 4;
#pragma unroll
          for (int r = 0; r < 4; ++r) {
            const int m = row0 + r;
            const int b = m >> 11, s = m & 2047;
            vtbuf[(((size_t)(b * NKVH + hh)) * HDIM + d) * S_LEN + s] =
                __float2bfloat16(acc[mf][ni][r]);
          }
        }
    }
  }
}

// ---------------- Attention phase A: 128-key blocks, barrier-free sub-tiles --
// r1's proven 16x16 math, restructured: stage 128 keys of K and V^T per
// iteration (one barrier pair per 128 keys instead of per 32), then process
// the four 32-key sub-tiles with qk(j+1) overlapping finish(j) IN-WAVE (no
// barriers between subs; Ps is per-wave). This divides the phase-lock /
// barrier-drain events by 4 and gives the compiler a full ILP window.
// Split-K tiers (128-key granularity, L = i2/4+1 blocks):
//   i2  0..23: nch=1 (final tiles, write abuf)     -> 24 chunks
//   i2 24..47: nch=2                               -> 48 chunks
//   i2 48..63: nch=3                               -> 48 chunks
// 120 chunks/(b,kvh), max 6 iters/block, grid 960. Diagonal blocks skip dead
// sub-tiles via block-uniform branches; element masks as in r1.
__global__ __launch_bounds__(256) void attn_partial(const bf16* __restrict__ qbuf,
                                                    const bf16* __restrict__ kbuf,
                                                    const bf16* __restrict__ vtbuf,
                                                    unsigned short* __restrict__ pnum,
                                                    float* __restrict__ plsum,
                                                    bf16* __restrict__ abuf)
{
  __shared__ unsigned short Ks[16384];   // [128 keys][128 d]  32KB
  __shared__ unsigned short Vs[16384];   // [128 d][128 keys]  32KB
  __shared__ unsigned short Ps[4][1280]; // per-wave [32][40]  10KB
  const int sidx = 119 - blockIdx.x;     // descending dispatch
  int i2, c, nch;
  if (sidx < 24)      { i2 = sidx;                          c = 0;     nch = 1; }
  else if (sidx < 72) { const int q = sidx - 24; i2 = 24 + (q >> 1); c = q & 1; nch = 2; }
  else                { const int q = sidx - 72; i2 = 48 + q / 3;    c = q % 3; nch = 3; }
  const int L = (i2 >> 2) + 1;           // 128-key blocks for this tile
  const int kb0 = (c * L) / nch, kb1 = ((c + 1) * L) / nch;
  const int kvh = blockIdx.y, b = blockIdx.z;
  const int t = threadIdx.x, w = t >> 6, lane = t & 63;
  const int m16 = lane & 15, quad = lane >> 4;
  const int h = kvh * 4 + w;

  const bf16* Qp = qbuf + (((size_t)(b * NHEADS + h)) * S_LEN + i2 * 32 + m16) * HDIM;
  short8 qf[2][4];
#pragma unroll
  for (int T = 0; T < 2; ++T)
#pragma unroll
    for (int cc = 0; cc < 4; ++cc)
      qf[T][cc] = *reinterpret_cast<const short8*>(Qp + (size_t)T * 16 * HDIM + cc * 32 + quad * 8);

  const bf16* Kp  = kbuf  + ((size_t)(b * NKVH + kvh)) * S_LEN * HDIM;
  const bf16* Vtp = vtbuf + ((size_t)(b * NKVH + kvh)) * HDIM * S_LEN;

  const int ls = lane >> 4;              // row within one async (4 rows/async)
  const int lc = lane & 15;              // 16B chunk within 256B row

  const floatx4 zf = {0.f, 0.f, 0.f, 0.f};
  floatx4 oacc[2][8];
#pragma unroll
  for (int T = 0; T < 2; ++T)
#pragma unroll
    for (int d = 0; d < 8; ++d) oacc[T][d] = zf;
  floatx4 lacc[2] = {zf, zf};
  unsigned short ones_s[8] = {0x3F80,0x3F80,0x3F80,0x3F80,0x3F80,0x3F80,0x3F80,0x3F80};
  const short8 ones = *reinterpret_cast<short8*>(ones_s);

  unsigned short* Pw = &Ps[w][0];

  // Stage one 128-key block: K rows (keys) and V^T rows (d) split over 4 waves,
  // 8+8 async_copy16 per wave. 16B-chunk XOR swizzle ^(row&7); linear LDS dest.
  auto stage_tile = [&](int kb) {
#pragma unroll
    for (int j = 0; j < 8; ++j) {
      const int r = w * 32 + j * 4 + ls;
      async_copy16(Kp + ((size_t)(kb * 128 + r)) * 128 + ((lc ^ (r & 7)) * 8),
                   &Ks[(w * 32 + j * 4) * 128]);
      async_copy16(Vtp + (size_t)r * 2048 + kb * 128 + ((lc ^ (r & 7)) * 8),
                   &Vs[(w * 32 + j * 4) * 128]);
    }
  };

  auto qk = [&](int sub, floatx4& s00, floatx4& s01, floatx4& s10, floatx4& s11) {
    s00 = zf; s01 = zf; s10 = zf; s11 = zf;
#pragma unroll
    for (int cc = 0; cc < 4; ++cc) {
      const int ch = ((cc * 4 + quad) ^ (m16 & 7)) * 8;
      short8 kf0 = *reinterpret_cast<const short8*>(&Ks[(sub * 32 + m16) * 128 + ch]);
      short8 kf1 = *reinterpret_cast<const short8*>(&Ks[(sub * 32 + 16 + m16) * 128 + ch]);
      s00 = __builtin_amdgcn_mfma_f32_16x16x32_bf16(qf[0][cc], kf0, s00, 0, 0, 0);
      s01 = __builtin_amdgcn_mfma_f32_16x16x32_bf16(qf[0][cc], kf1, s01, 0, 0, 0);
      s10 = __builtin_amdgcn_mfma_f32_16x16x32_bf16(qf[1][cc], kf0, s10, 0, 0, 0);
      s11 = __builtin_amdgcn_mfma_f32_16x16x32_bf16(qf[1][cc], kf1, s11, 0, 0, 0);
    }
  };

  auto finish = [&](int kb, int sub, const floatx4& s00, const floatx4& s01,
                    const floatx4& s10, const floatx4& s11) {
    const int ks = kb * 128 + sub * 32;
#pragma unroll
    for (int T = 0; T < 2; ++T) {
      const floatx4& sa = T ? s10 : s00;
      const floatx4& sb = T ? s11 : s01;
#pragma unroll
      for (int r = 0; r < 4; ++r) {
        const int row = i2 * 32 + T * 16 + quad * 4 + r;
        const float p0 = (ks + m16      > row) ? 0.f : __expf(sa[r]);
        const float p1 = (ks + 16 + m16 > row) ? 0.f : __expf(sb[r]);
        Pw[(T * 16 + quad * 4 + r) * 40 + m16]      = cvt1(p0);
        Pw[(T * 16 + quad * 4 + r) * 40 + 16 + m16] = cvt1(p1);
      }
    }
    const short8 pa0 = *reinterpret_cast<const short8*>(&Pw[m16 * 40 + quad * 8]);
    const short8 pa1 = *reinterpret_cast<const short8*>(&Pw[(16 + m16) * 40 + quad * 8]);
    lacc[0] = __builtin_amdgcn_mfma_f32_16x16x32_bf16(pa0, ones, lacc[0], 0, 0, 0);
    lacc[1] = __builtin_amdgcn_mfma_f32_16x16x32_bf16(pa1, ones, lacc[1], 0, 0, 0);
#pragma unroll
    for (int dt = 0; dt < 8; ++dt) {
      short8 vfr = *reinterpret_cast<const short8*>(
          &Vs[(dt * 16 + m16) * 128 + (((sub * 4 + quad) ^ (m16 & 7)) * 8)]);
      oacc[0][dt] = __builtin_amdgcn_mfma_f32_16x16x32_bf16(pa0, vfr, oacc[0][dt], 0, 0, 0);
      oacc[1][dt] = __builtin_amdgcn_mfma_f32_16x16x32_bf16(pa1, vfr, oacc[1][dt], 0, 0, 0);
    }
  };

  for (int kb = kb0; kb < kb1; ++kb) {
    __syncthreads();                      // previous block's compute done
    stage_tile(kb);
    __syncthreads();                      // staging drained (vmcnt0 implied)
    const int rem = i2 - 4 * kb + 1;      // live sub-tiles (>=4 off-diagonal)
    floatx4 a0, a1, a2, a3, b0, b1, b2, b3;
    qk(0, a0, a1, a2, a3);
    if (rem == 1) { finish(kb, 0, a0, a1, a2, a3); }
    else {
      qk(1, b0, b1, b2, b3);
      finish(kb, 0, a0, a1, a2, a3);
      if (rem == 2) { finish(kb, 1, b0, b1, b2, b3); }
      else {
        qk(2, a0, a1, a2, a3);
        finish(kb, 1, b0, b1, b2, b3);
        if (rem == 3) { finish(kb, 2, a0, a1, a2, a3); }
        else {
          qk(3, b0, b1, b2, b3);
          finish(kb, 2, a0, a1, a2, a3);
          finish(kb, 3, b0, b1, b2, b3);
        }
      }
    }
  }

  if (nch == 1) {
    // final tiles (i2 0..23): divide by row-sum, write abuf directly
#pragma unroll
    for (int T = 0; T < 2; ++T) {
      float invl[4];
#pragma unroll
      for (int r = 0; r < 4; ++r) invl[r] = 1.0f / lacc[T][r];
      bf16* op = abuf + (((size_t)b * S_LEN + i2 * 32 + T * 16 + quad * 4) * NHEADS + h) * HDIM + m16;
#pragma unroll
      for (int dt = 0; dt < 8; ++dt)
#pragma unroll
        for (int r = 0; r < 4; ++r)
          op[(size_t)r * NHEADS * HDIM + dt * 16] = __float2bfloat16(oacc[T][dt][r] * invl[r]);
    }
  } else {
    // multi-chunk slots: i2 24..47 -> (i2-24)*2 ; i2 48..63 -> 48+(i2-48)*3
    const int base = (i2 < 48) ? (i2 - 24) * 2 : 48 + (i2 - 48) * 3;
    const int slot = (b * NHEADS + h) * 96 + base + c;
    unsigned short* np = pnum + (size_t)slot * 4096;
#pragma unroll
    for (int T = 0; T < 2; ++T)
#pragma unroll
      for (int dt = 0; dt < 8; ++dt)
#pragma unroll
        for (int r = 0; r < 4; ++r)
          np[(T * 16 + quad * 4 + r) * 128 + dt * 16 + m16] = cvt1(oacc[T][dt][r]);
    if (m16 == 0) {
#pragma unroll
      for (int T = 0; T < 2; ++T)
#pragma unroll
        for (int r = 0; r < 4; ++r)
          plsum[slot * 32 + T * 16 + quad * 4 + r] = lacc[T][r];
    }
  }
}

// ---------------- Attention phase B: combine multi-chunk tiles (i2 24..63) ---
__global__ __launch_bounds__(256) void attn_combine(const unsigned short* __restrict__ pnum,
                                                    const float* __restrict__ plsum,
                                                    bf16* __restrict__ abuf)
{
  const int i = blockIdx.x;                          // 0..79: 40 tiles x 2 halves
  const int i2 = 24 + (i >> 1), lr0 = (i & 1) * 16;
  const int h = blockIdx.y, b = blockIdx.z;
  const int t = threadIdx.x, row16 = t >> 4, c0 = (t & 15) * 8;
  const int lr = lr0 + row16;
  const int nch  = (i2 < 48) ? 2 : 3;
  const int base = (i2 < 48) ? (i2 - 24) * 2 : 48 + (i2 - 48) * 3;
  const int hb = (b * NHEADS + h) * 96 + base;
  float acc[8] = {0.f,0.f,0.f,0.f,0.f,0.f,0.f,0.f};
  float lsum = 0.f;
  for (int c = 0; c < nch; ++c) {
    const unsigned short* np = pnum + (size_t)(hb + c) * 4096 + lr * 128 + c0;
    const short8 v = *reinterpret_cast<const short8*>(np);
#pragma unroll
    for (int j = 0; j < 8; ++j) acc[j] += us2f(((unsigned short*)&v)[j]);
    lsum += plsum[(hb + c) * 32 + lr];
  }
  const float invl = 1.0f / lsum;
  unsigned short o[8];
#pragma unroll
  for (int j = 0; j < 8; ++j) o[j] = cvt1(acc[j] * invl);
  *reinterpret_cast<short8*>(abuf + (((size_t)b * S_LEN + i2 * 32 + lr) * NHEADS + h) * HDIM + c0)
      = *reinterpret_cast<short8*>(o);
}

extern "C" void kernel_launch(void* const* d_in, const int* in_sizes, int n_in,
                              void* d_out, int out_size, void* d_ws, size_t ws_size,
                              hipStream_t stream) {
  const float* hidden_f = (const float*)d_in[0];
  const float* wqkv_f   = (const float*)d_in[1];
  const float* wout_f   = (const float*)d_in[2];
  float* out = (float*)d_out;

  char* ws = (char*)d_ws;
  bf16* hbf    = (bf16*)(ws);                    // [4096,2048]   (dead after gemm0)
  bf16* wqkvbf = (bf16*)(ws + 16777216);         // [3072,2048]   (dead after gemm0)
  bf16* woutbf = (bf16*)(ws + 29360128);         // [2048,2048]
  bf16* qbuf   = (bf16*)(ws + 37748736);         // [B,NH,S,HD]
  bf16* kbuf   = (bf16*)(ws + 54525952);         // [B,NKV,S,HD]
  bf16* vtbuf  = (bf16*)(ws + 58720256);         // [B,NKV,HD,S]
  bf16* abuf   = (bf16*)(ws + 62914560);         // [B,S,NH,HD]
  unsigned short* pnum = (unsigned short*)(ws);  // overlay: 3072 x 8KB = 25.2 MB
  float* plsum = (float*)(ws + 79691776);        // 3072 x 32 fp32 (0.39 MB)

  cvt_all<<<9216, 256, 0, stream>>>(hidden_f, wqkv_f, wout_f, (unsigned short*)ws);

  gemm8<0><<<dim3(12, 16), 512, 0, stream>>>(hbf, wqkvbf, qbuf, kbuf, vtbuf, nullptr);
  attn_partial<<<dim3(120, 4, 2), 256, 0, stream>>>(qbuf, kbuf, vtbuf, pnum, plsum, abuf);
  attn_combine<<<dim3(80, 16, 2), 256, 0, stream>>>(pnum, plsum, abuf);
  gemm8<1><<<dim3(8, 32), 512, 0, stream>>>(abuf, woutbf, nullptr, nullptr, nullptr, out);
}